// Round 6
// baseline (189.467 us; speedup 1.0000x reference)
//
#include <hip/hip_runtime.h>
#include <hip/hip_cooperative_groups.h>

namespace cg = cooperative_groups;

// Problem constants
#define SOM_DIM 512
#define SOM_ROWS 65536          // 256*256
#define SOM_ELEMS (SOM_ROWS * SOM_DIM)

// Fused cooperative geometry: 1024 blocks x 256 thr = 4 blocks/CU, 16 waves/CU
#define FGRID 1024
#define FWAVES 4
#define ROWS_PER_WAVE 16        // 1024*4*16 = 65536 rows
#define NPART (FGRID * FWAVES)  // 4096 packed partials (32 KB in d_ws)

typedef float f32x4 __attribute__((ext_vector_type(4)));
typedef float f32x2 __attribute__((ext_vector_type(2)));
typedef unsigned long long u64;

// ================= Fused cooperative kernel (no stash) =================
// Phase A: distances + per-wave packed (dist|idx) partial.
// grid.sync. Block-reduce partials. Phase B: update, re-reading weights from
// L2/L3 (reverse row order -> hit the LRU tail of phase A's reads in L2).
__global__ __launch_bounds__(256, 4) void som_fused(
    const float* __restrict__ w, const float* __restrict__ in,
    const int* __restrict__ epoch_p, u64* __restrict__ part,
    float* __restrict__ out) {
  const int wave = threadIdx.x >> 6;
  const int lane = threadIdx.x & 63;
  const int row0 = blockIdx.x * (FWAVES * ROWS_PER_WAVE) + wave * ROWS_PER_WAVE;

  // input vector chunks matching the f32x2 lane-contiguous layout
  const f32x2* in2 = (const f32x2*)in;
  f32x2 iv[4];
#pragma unroll
  for (int s = 0; s < 4; ++s) iv[s] = in2[s * 64 + lane];

  float bd = 3.4e38f;
  int bi = SOM_ROWS;

  // ---- Phase A: distance + per-wave argmin ----
#pragma unroll 4
  for (int r = 0; r < ROWS_PER_WAVE; ++r) {
    const f32x2* wr = (const f32x2*)(w + (size_t)(row0 + r) * SOM_DIM);
    float acc = 0.f;
#pragma unroll
    for (int s = 0; s < 4; ++s) {
      f32x2 d = wr[s * 64 + lane] - iv[s];
      acc += d.x * d.x + d.y * d.y;
    }
#pragma unroll
    for (int off = 32; off; off >>= 1) acc += __shfl_xor(acc, off, 64);
    // rows ascend -> strict < keeps first occurrence (jnp.argmin semantics)
    if (acc < bd) { bd = acc; bi = row0 + r; }
  }

  if (lane == 0)
    part[blockIdx.x * FWAVES + wave] =
        ((u64)__float_as_uint(bd) << 32) | (unsigned int)bi;

  cg::this_grid().sync();

  // ---- block-level reduce of NPART packed partials (L2-resident, 32 KB) ----
  __shared__ u64 sp[256];
  u64 m = ~0ull;
  for (int i = threadIdx.x; i < NPART; i += 256) {
    u64 v = part[i];
    m = (v < m) ? v : m;
  }
  sp[threadIdx.x] = m;
  __syncthreads();
  for (int s = 128; s; s >>= 1) {
    if ((int)threadIdx.x < s) {
      if (sp[threadIdx.x + s] < sp[threadIdx.x]) sp[threadIdx.x] = sp[threadIdx.x + s];
    }
    __syncthreads();
  }
  const int bidx = (int)(unsigned int)(sp[0] & 0xFFFFFFFFull);
  const int br = bidx >> 8;   // N = 256
  const int bc = bidx & 255;

  if (blockIdx.x == 0 && threadIdx.x == 0) {
    out[0] = (float)br;
    out[1] = (float)bc;
  }

  // ---- Phase B: update (reverse order for L2 LRU hits) ----
  const float lr = 1.0f - (float)epoch_p[0] / 100.0f;
  const float alpha_op = 0.3f * lr;
  const float sigma_op = 128.0f * lr;
  const float inv_s2 = 1.0f / (sigma_op * sigma_op);

#pragma unroll 2
  for (int r = ROWS_PER_WAVE - 1; r >= 0; --r) {
    const int row = row0 + r;
    const int rr = (row >> 8) - br;
    const int cc = (row & 255) - bc;
    const float mult = alpha_op * __expf(-(float)(rr * rr + cc * cc) * inv_s2);
    const f32x2* wr = (const f32x2*)(w + (size_t)row * SOM_DIM);
    f32x2* ob = (f32x2*)(out + 2 + (size_t)row * SOM_DIM);  // 8B-aligned
#pragma unroll
    for (int s = 0; s < 4; ++s) {
      f32x2 wv = wr[s * 64 + lane];
      ob[s * 64 + lane] = wv + mult * (iv[s] - wv);
    }
  }
}

// ================= Fallback path (R4 two-kernel, proven 69 µs) =================
#define NB 2048
__global__ __launch_bounds__(256) void som_bmu_partial(
    const float* __restrict__ w, const float* __restrict__ in,
    u64* __restrict__ part) {
  __shared__ float s_in[SOM_DIM];
  for (int i = threadIdx.x; i < SOM_DIM; i += 256) s_in[i] = in[i];
  __syncthreads();
  const int wave = threadIdx.x >> 6;
  const int lane = threadIdx.x & 63;
  const int globalWave = blockIdx.x * 4 + wave;
  const int nWaves = NB * 4;
  float bd = 3.4e38f;
  int bi = SOM_ROWS;
  const f32x4* in4 = (const f32x4*)s_in;
  for (int row = globalWave; row < SOM_ROWS; row += nWaves) {
    const f32x4* wr = (const f32x4*)(w + (size_t)row * SOM_DIM);
    float acc = 0.f;
#pragma unroll
    for (int k = 0; k < 2; ++k) {
      f32x4 wv = wr[lane + 64 * k];
      f32x4 iv = in4[lane + 64 * k];
      f32x4 d = wv - iv;
      acc += d.x * d.x + d.y * d.y + d.z * d.z + d.w * d.w;
    }
#pragma unroll
    for (int off = 32; off; off >>= 1) acc += __shfl_xor(acc, off, 64);
    if (acc < bd) { bd = acc; bi = row; }
  }
  u64 pk = ((u64)__float_as_uint(bd) << 32) | (unsigned int)bi;
  __shared__ u64 sp[4];
  if (lane == 0) sp[wave] = pk;
  __syncthreads();
  if (threadIdx.x == 0) {
    u64 mm = sp[0];
#pragma unroll
    for (int k = 1; k < 4; ++k) mm = (sp[k] < mm) ? sp[k] : mm;
    part[blockIdx.x] = mm;
  }
}

__global__ __launch_bounds__(256) void som_update(
    const float* __restrict__ w, const float* __restrict__ in,
    const int* __restrict__ epoch_p, const u64* __restrict__ part,
    float* __restrict__ out) {
  __shared__ u64 sp[256];
  u64 m = ~0ull;
  for (int i = threadIdx.x; i < NB; i += 256) {
    u64 v = part[i];
    m = (v < m) ? v : m;
  }
  sp[threadIdx.x] = m;
  __syncthreads();
  for (int s = 128; s; s >>= 1) {
    if ((int)threadIdx.x < s) {
      if (sp[threadIdx.x + s] < sp[threadIdx.x]) sp[threadIdx.x] = sp[threadIdx.x + s];
    }
    __syncthreads();
  }
  const int bidx = (int)(unsigned int)(sp[0] & 0xFFFFFFFFull);
  const int br = bidx >> 8;
  const int bc = bidx & 255;
  if (blockIdx.x == 0 && threadIdx.x == 0) {
    out[0] = (float)br;
    out[1] = (float)bc;
  }
  const float lr = 1.0f - (float)epoch_p[0] / 100.0f;
  const float alpha_op = 0.3f * lr;
  const float sigma_op = 128.0f * lr;
  const float inv_s2 = 1.0f / (sigma_op * sigma_op);
  const f32x2* w2 = (const f32x2*)w;
  const f32x2* in2 = (const f32x2*)in;
  f32x2* o2 = (f32x2*)(out + 2);
  const int total2 = SOM_ELEMS / 2;
  const int stride = NB * 256;
  for (int j = blockIdx.x * 256 + threadIdx.x; j < total2; j += stride) {
    const int row = j >> 8;
    const int rr = (row >> 8) - br;
    const int cc = (row & 255) - bc;
    const float mult = alpha_op * __expf(-(float)(rr * rr + cc * cc) * inv_s2);
    f32x2 wv = w2[j];
    f32x2 iv = in2[j & 255];
    o2[j] = wv + mult * (iv - wv);
  }
}

extern "C" void kernel_launch(void* const* d_in, const int* in_sizes, int n_in,
                              void* d_out, int out_size, void* d_ws, size_t ws_size,
                              hipStream_t stream) {
  const float* input_vector = (const float*)d_in[0];
  const float* weights = (const float*)d_in[1];
  const int* epoch = (const int*)d_in[2];
  float* out = (float*)d_out;
  u64* part = (u64*)d_ws;  // [NPART] = 32 KB

  void* kargs[] = {(void*)&weights, (void*)&input_vector, (void*)&epoch,
                   (void*)&part, (void*)&out};
  hipError_t e = hipLaunchCooperativeKernel((const void*)som_fused,
                                            dim3(FGRID), dim3(256), kargs,
                                            0, stream);
  if (e != hipSuccess) {
    // cooperative launch unavailable -> proven two-kernel path
    som_bmu_partial<<<NB, 256, 0, stream>>>(weights, input_vector, part);
    som_update<<<NB, 256, 0, stream>>>(weights, input_vector, epoch, part, out);
  }
}

// Round 7
// 70.795 us; speedup vs baseline: 2.6763x; 2.6763x over previous
//
#include <hip/hip_runtime.h>

// Problem constants (from reference)
#define SOM_M 256
#define SOM_N 256
#define SOM_DIM 512
#define SOM_ROWS (SOM_M * SOM_N)          // 65536
#define SOM_ELEMS (SOM_ROWS * SOM_DIM)    // 33554432
#define NB 2048                           // blocks for both kernels

typedef float f32x4 __attribute__((ext_vector_type(4)));
typedef float f32x2 __attribute__((ext_vector_type(2)));
typedef unsigned long long u64;

// ---------------- Kernel 1: per-block BMU partial argmin ----------------
// One wave (64 lanes) per row; lane loads 8 floats (2x float4), butterfly
// reduce sum of squared diffs; block writes packed (dist|idx) u64 partial.
// dist >= 0 so float bits are monotone as u32; equal dist -> smaller row
// wins, matching jnp.argmin first-occurrence semantics.
__global__ __launch_bounds__(256) void som_bmu_partial(
    const float* __restrict__ w, const float* __restrict__ in,
    u64* __restrict__ part) {
  __shared__ float s_in[SOM_DIM];
  for (int i = threadIdx.x; i < SOM_DIM; i += 256) s_in[i] = in[i];
  __syncthreads();

  const int wave = threadIdx.x >> 6;
  const int lane = threadIdx.x & 63;
  const int globalWave = blockIdx.x * 4 + wave;
  const int nWaves = NB * 4;

  float bd = 3.4e38f;
  int bi = SOM_ROWS;

  const f32x4* in4 = (const f32x4*)s_in;
  for (int row = globalWave; row < SOM_ROWS; row += nWaves) {
    const f32x4* wr = (const f32x4*)(w + (size_t)row * SOM_DIM);
    float acc = 0.f;
#pragma unroll
    for (int k = 0; k < 2; ++k) {
      f32x4 wv = wr[lane + 64 * k];
      f32x4 iv = in4[lane + 64 * k];
      f32x4 d = wv - iv;
      acc += d.x * d.x + d.y * d.y + d.z * d.z + d.w * d.w;
    }
#pragma unroll
    for (int off = 32; off; off >>= 1) acc += __shfl_xor(acc, off, 64);
    // rows visited in increasing order per wave -> strict < keeps first min
    if (acc < bd) { bd = acc; bi = row; }
  }

  u64 pk = ((u64)__float_as_uint(bd) << 32) | (unsigned int)bi;

  __shared__ u64 sp[4];
  if (lane == 0) sp[wave] = pk;
  __syncthreads();
  if (threadIdx.x == 0) {
    u64 m = sp[0];
#pragma unroll
    for (int k = 1; k < 4; ++k) m = (sp[k] < m) ? sp[k] : m;
    part[blockIdx.x] = m;
  }
}

// ---------------- Kernel 2: inline final reduce + weight update ----------------
// Each block first min-reduces the NB packed partials (L2-resident, ~16KB),
// then: new_w = w + alpha_op * exp(-bmu_dist_sq / sigma_op^2) * (in - w)
// Weight re-loads are NON-TEMPORAL: a re-read line is dead (never touched
// again), so the evict-first hint steers L3 victim selection onto consumed
// lines instead of the not-yet-read weight rows (which k1 left resident).
__global__ __launch_bounds__(256) void som_update(
    const float* __restrict__ w, const float* __restrict__ in,
    const int* __restrict__ epoch_p, const u64* __restrict__ part,
    float* __restrict__ out /* d_out base */) {
  // --- final argmin reduce (all blocks, redundant but cheap) ---
  __shared__ u64 sp[256];
  u64 m = ~0ull;
  for (int i = threadIdx.x; i < NB; i += 256) {
    u64 v = part[i];
    m = (v < m) ? v : m;
  }
  sp[threadIdx.x] = m;
  __syncthreads();
  for (int s = 128; s; s >>= 1) {
    if ((int)threadIdx.x < s) {
      if (sp[threadIdx.x + s] < sp[threadIdx.x]) sp[threadIdx.x] = sp[threadIdx.x + s];
    }
    __syncthreads();
  }
  const int bidx = (int)(unsigned int)(sp[0] & 0xFFFFFFFFull);
  const int br = bidx >> 8;   // N = 256
  const int bc = bidx & 255;

  if (blockIdx.x == 0 && threadIdx.x == 0) {
    out[0] = (float)br;
    out[1] = (float)bc;
  }

  const float lr = 1.0f - (float)epoch_p[0] / 100.0f;
  const float alpha_op = 0.3f * lr;
  const float sigma_op = 128.0f * lr;
  const float inv_s2 = 1.0f / (sigma_op * sigma_op);

  const f32x2* w2 = (const f32x2*)w;
  const f32x2* in2 = (const f32x2*)in;
  f32x2* o2 = (f32x2*)(out + 2);  // 8B-aligned

  const int total2 = SOM_ELEMS / 2;  // 16777216
  const int stride = NB * 256;
  for (int j = blockIdx.x * 256 + threadIdx.x; j < total2; j += stride) {
    const int row = j >> 8;             // element e = 2j, row = e >> 9
    const int rr = (row >> 8) - br;
    const int cc = (row & 255) - bc;
    const float d2 = (float)(rr * rr + cc * cc);
    const float mult = alpha_op * __expf(-d2 * inv_s2);

    f32x2 wv = __builtin_nontemporal_load(&w2[j]);  // evict-first: line is dead after this
    f32x2 iv = in2[j & 255];
    f32x2 r = wv + mult * (iv - wv);
    o2[j] = r;   // regular store (nt stores regressed in R2)
  }
}

extern "C" void kernel_launch(void* const* d_in, const int* in_sizes, int n_in,
                              void* d_out, int out_size, void* d_ws, size_t ws_size,
                              hipStream_t stream) {
  const float* input_vector = (const float*)d_in[0];
  const float* weights = (const float*)d_in[1];
  const int* epoch = (const int*)d_in[2];
  float* out = (float*)d_out;

  u64* part = (u64*)d_ws;  // [NB] = 16 KB

  som_bmu_partial<<<NB, 256, 0, stream>>>(weights, input_vector, part);
  som_update<<<NB, 256, 0, stream>>>(weights, input_vector, epoch, part, out);
}

// Round 8
// 69.582 us; speedup vs baseline: 2.7229x; 1.0174x over previous
//
#include <hip/hip_runtime.h>

// Problem constants (from reference)
#define SOM_M 256
#define SOM_N 256
#define SOM_DIM 512
#define SOM_ROWS (SOM_M * SOM_N)          // 65536
#define SOM_ELEMS (SOM_ROWS * SOM_DIM)    // 33554432
#define NB 2048                           // blocks for both kernels

typedef float f32x4 __attribute__((ext_vector_type(4)));
typedef float f32x2 __attribute__((ext_vector_type(2)));
typedef unsigned long long u64;

// ---------------- Kernel 1: per-block BMU partial argmin ----------------
// One wave (64 lanes) per row; lane loads 8 floats (2x float4), butterfly
// reduce sum of squared diffs; block writes packed (dist|idx) u64 partial.
// dist >= 0 so float bits are monotone as u32; equal dist -> smaller row
// wins, matching jnp.argmin first-occurrence semantics.
__global__ __launch_bounds__(256) void som_bmu_partial(
    const float* __restrict__ w, const float* __restrict__ in,
    u64* __restrict__ part) {
  __shared__ float s_in[SOM_DIM];
  for (int i = threadIdx.x; i < SOM_DIM; i += 256) s_in[i] = in[i];
  __syncthreads();

  const int wave = threadIdx.x >> 6;
  const int lane = threadIdx.x & 63;
  const int globalWave = blockIdx.x * 4 + wave;
  const int nWaves = NB * 4;

  float bd = 3.4e38f;
  int bi = SOM_ROWS;

  const f32x4* in4 = (const f32x4*)s_in;
  for (int row = globalWave; row < SOM_ROWS; row += nWaves) {
    const f32x4* wr = (const f32x4*)(w + (size_t)row * SOM_DIM);
    float acc = 0.f;
#pragma unroll
    for (int k = 0; k < 2; ++k) {
      f32x4 wv = wr[lane + 64 * k];
      f32x4 iv = in4[lane + 64 * k];
      f32x4 d = wv - iv;
      acc += d.x * d.x + d.y * d.y + d.z * d.z + d.w * d.w;
    }
#pragma unroll
    for (int off = 32; off; off >>= 1) acc += __shfl_xor(acc, off, 64);
    // rows visited in increasing order per wave -> strict < keeps first min
    if (acc < bd) { bd = acc; bi = row; }
  }

  u64 pk = ((u64)__float_as_uint(bd) << 32) | (unsigned int)bi;

  __shared__ u64 sp[4];
  if (lane == 0) sp[wave] = pk;
  __syncthreads();
  if (threadIdx.x == 0) {
    u64 m = sp[0];
#pragma unroll
    for (int k = 1; k < 4; ++k) m = (sp[k] < m) ? sp[k] : m;
    part[blockIdx.x] = m;
  }
}

// ---------------- Kernel 2: inline final reduce + weight update ----------------
// Each block first min-reduces the NB packed partials (L2-resident, ~16KB),
// then: new_w = w + alpha_op * exp(-bmu_dist_sq / sigma_op^2) * (in - w)
// Processing is symmetric at f32x2 granularity so BOTH the weight loads and
// the (out+2)-offset stores are fully contiguous per wave-instruction.
__global__ __launch_bounds__(256) void som_update(
    const float* __restrict__ w, const float* __restrict__ in,
    const int* __restrict__ epoch_p, const u64* __restrict__ part,
    float* __restrict__ out /* d_out base */) {
  // --- final argmin reduce (all blocks, redundant but cheap) ---
  __shared__ u64 sp[256];
  u64 m = ~0ull;
  for (int i = threadIdx.x; i < NB; i += 256) {
    u64 v = part[i];
    m = (v < m) ? v : m;
  }
  sp[threadIdx.x] = m;
  __syncthreads();
  for (int s = 128; s; s >>= 1) {
    if ((int)threadIdx.x < s) {
      if (sp[threadIdx.x + s] < sp[threadIdx.x]) sp[threadIdx.x] = sp[threadIdx.x + s];
    }
    __syncthreads();
  }
  const int bidx = (int)(unsigned int)(sp[0] & 0xFFFFFFFFull);
  const int br = bidx >> 8;   // N = 256
  const int bc = bidx & 255;

  if (blockIdx.x == 0 && threadIdx.x == 0) {
    out[0] = (float)br;
    out[1] = (float)bc;
  }

  const float lr = 1.0f - (float)epoch_p[0] / 100.0f;
  const float alpha_op = 0.3f * lr;
  const float sigma_op = 128.0f * lr;
  const float inv_s2 = 1.0f / (sigma_op * sigma_op);

  const f32x2* w2 = (const f32x2*)w;
  const f32x2* in2 = (const f32x2*)in;
  f32x2* o2 = (f32x2*)(out + 2);  // 8B-aligned

  const int total2 = SOM_ELEMS / 2;  // 16777216
  const int stride = NB * 256;
  for (int j = blockIdx.x * 256 + threadIdx.x; j < total2; j += stride) {
    const int row = j >> 8;             // element e = 2j, row = e >> 9
    const int rr = (row >> 8) - br;
    const int cc = (row & 255) - bc;
    const float d2 = (float)(rr * rr + cc * cc);
    const float mult = alpha_op * __expf(-d2 * inv_s2);

    f32x2 wv = w2[j];
    f32x2 iv = in2[j & 255];
    f32x2 r = wv + mult * (iv - wv);
    o2[j] = r;
  }
}

extern "C" void kernel_launch(void* const* d_in, const int* in_sizes, int n_in,
                              void* d_out, int out_size, void* d_ws, size_t ws_size,
                              hipStream_t stream) {
  const float* input_vector = (const float*)d_in[0];
  const float* weights = (const float*)d_in[1];
  const int* epoch = (const int*)d_in[2];
  float* out = (float*)d_out;

  u64* part = (u64*)d_ws;  // [NB] = 16 KB

  som_bmu_partial<<<NB, 256, 0, stream>>>(weights, input_vector, part);
  som_update<<<NB, 256, 0, stream>>>(weights, input_vector, epoch, part, out);
}